// Round 19
// baseline (446.203 us; speedup 1.0000x reference)
//
#include <hip/hip_runtime.h>
#include <cstdint>

typedef _Float16 f16;
typedef __attribute__((ext_vector_type(8))) _Float16 f16x8;
typedef __attribute__((ext_vector_type(4))) _Float16 f16x4;
typedef __attribute__((ext_vector_type(4))) float f32x4;

typedef __attribute__((address_space(1))) void gvoid_t;
typedef __attribute__((address_space(3))) void lvoid_t;

// async global->LDS, 16B per lane. LDS dest wave-uniform base; HW adds lane*16.
__device__ __forceinline__ void async_copy16(void* lds, const void* g) {
  __builtin_amdgcn_global_load_lds((gvoid_t*)(uintptr_t)g, (lvoid_t*)lds, 16, 0, 0);
}

#define BARRIER()   __builtin_amdgcn_s_barrier()
#define SCHEDBAR()  __builtin_amdgcn_sched_barrier(0)
#define VMCNT(n)    do { SCHEDBAR(); asm volatile("s_waitcnt vmcnt(" #n ")"); SCHEDBAR(); } while (0)

#define MFMA16(a, b, c) __builtin_amdgcn_mfma_f32_16x16x32_f16((a), (b), (c), 0, 0, 0)

// LDS declared ONCE per kernel and passed in (r18 lesson: two inlined
// gemm_body instantiations each got their own 128KB -> 256KB compile fail).
struct Smem {
  f16 AH0a[8192]; f16 AH0b[8192];
  f16 AH1a[8192]; f16 AH1b[8192];
  f16 BH0a[8192]; f16 BH0b[8192];
  f16 BH1a[8192]; f16 BH1b[8192];
};

// 256x256 tile, BK=64, 8 waves (2M x 4N).  4 barrier-segments per 2 K-tiles
// (r16 schedule, converged).  Epilogue modes:
//   EPI=1: f16 = acc*scale + bias[col]
//   EPI=2: f16 = exp(acc*scale); accumulate rowsum[row] via 16-lane reduce +
//          atomicAdd  (fused softmax numerator; max-free exp safe: |s|<~3.5)
//   EPI=3: f32 = acc / rowsum[row] + bias[col]  (denominator folded in)
template<int EPI>
__device__ __forceinline__ void gemm_body(Smem& sm,
                                          const f16* __restrict__ Ab, int lda,
                                          const f16* __restrict__ Bb, int ldb,
                                          void* __restrict__ Cz, int ldc,
                                          const float* __restrict__ bias,
                                          float* __restrict__ rs,
                                          float scale, int K)
{
  const int tid = threadIdx.x, lane = tid & 63, wave = tid >> 6;
  const int wr = wave >> 2, wc = wave & 3;       // wave -> (M half, N quarter)
  const int l15 = lane & 15, lk = lane >> 4;

  // XCD-aware bijective swizzle of the flattened x-y grid (z untouched)
  int lin = blockIdx.y * gridDim.x + blockIdx.x;
  const int nxy = gridDim.x * gridDim.y;
  if ((nxy & 7) == 0) lin = (lin & 7) * (nxy >> 3) + (lin >> 3);
  const int bx = lin % gridDim.x, by = lin / gridDim.x;

  const long brow = (long)by * 256, bcol = (long)bx * 256;

  // staging: slot=tid covers (row=tid>>3 [+64 for 2nd instr], col8=tid&7) of a
  // 128x64 half; global col-block pre-swizzled gc8 = (tid&7)^(row&7) so the
  // ds_read side applies the same XOR (both-sides-or-neither).
  const int r0  = tid >> 3;                  // 0..63
  const int gc8 = (tid & 7) ^ (r0 & 7);      // (r0+64)&7 == r0&7
  const int sdst = wave * 512;               // wave-uniform elem offset

  const f16* gAa = Ab + (brow + r0) * (long)lda + gc8 * 8;
  const f16* gAb = gAa + 128L * lda;
  const f16* gBa = Bb + (bcol + r0) * (long)ldb + gc8 * 8;
  const f16* gBb = gBa + 128L * ldb;

#define STG(BUF, G, LD, KOFF) { \
    async_copy16(BUF + sdst,        (G) + (KOFF)); \
    async_copy16(BUF + 4096 + sdst, (G) + 64L * (LD) + (KOFF)); }

  // per-wave source halves
  const f16* myA0 = wr ? sm.AH0b : sm.AH0a;
  const f16* myA1 = wr ? sm.AH1b : sm.AH1a;
  const f16* myB0 = (wc & 2) ? sm.BH0b : sm.BH0a;
  const f16* myB1 = (wc & 2) ? sm.BH1b : sm.BH1a;

  // frag read addressing: lr = m16 + l15 (m16 mult of 16 => lr&7 == l15&7)
  const int x8   = l15 & 7;
  const int cb0  = (lk ^ x8) * 8;            // kk=0 col bytes/2
  const int cb1  = ((4 | lk) ^ x8) * 8;      // kk=1
  const int lbA  = l15 * 64;
  const int lbB  = ((wc & 1) * 64 + l15) * 64;

#define RDA4(SRC, MP) { \
    af[0] = *(const f16x8*)&(SRC)[lbA + (2*(MP))   * 1024 + cb0]; \
    af[1] = *(const f16x8*)&(SRC)[lbA + (2*(MP))   * 1024 + cb1]; \
    af[2] = *(const f16x8*)&(SRC)[lbA + (2*(MP)+1) * 1024 + cb0]; \
    af[3] = *(const f16x8*)&(SRC)[lbA + (2*(MP)+1) * 1024 + cb1]; }

#define RDB8(SRC) { \
    bf[0][0] = *(const f16x8*)&(SRC)[lbB + 0 * 1024 + cb0]; \
    bf[1][0] = *(const f16x8*)&(SRC)[lbB + 0 * 1024 + cb1]; \
    bf[0][1] = *(const f16x8*)&(SRC)[lbB + 1 * 1024 + cb0]; \
    bf[1][1] = *(const f16x8*)&(SRC)[lbB + 1 * 1024 + cb1]; \
    bf[0][2] = *(const f16x8*)&(SRC)[lbB + 2 * 1024 + cb0]; \
    bf[1][2] = *(const f16x8*)&(SRC)[lbB + 2 * 1024 + cb1]; \
    bf[0][3] = *(const f16x8*)&(SRC)[lbB + 3 * 1024 + cb0]; \
    bf[1][3] = *(const f16x8*)&(SRC)[lbB + 3 * 1024 + cb1]; }

#define CLUSTER(MP) { \
    __builtin_amdgcn_s_setprio(1); \
    _Pragma("unroll") \
    for (int n = 0; n < 4; ++n) { \
      f32x4 t = MFMA16(af[0], bf[0][n], acc[2*(MP)][n]); \
      acc[2*(MP)][n] = MFMA16(af[1], bf[1][n], t); \
    } \
    _Pragma("unroll") \
    for (int n = 0; n < 4; ++n) { \
      f32x4 t = MFMA16(af[2], bf[0][n], acc[2*(MP)+1][n]); \
      acc[2*(MP)+1][n] = MFMA16(af[3], bf[1][n], t); \
    } \
    __builtin_amdgcn_s_setprio(0); }

  f32x4 acc[8][4] = {};
  f16x8 af[4], bf[2][4];
  const int NIT = K >> 7;                    // K/128

  // prologue: B0, A0, B1-half-a (10 instrs); vmcnt(2) leaves BH1a in flight.
  STG(sm.BH0a, gBa, ldb, 0);  STG(sm.BH0b, gBb, ldb, 0);
  STG(sm.AH0a, gAa, lda, 0);  STG(sm.AH0b, gAb, lda, 0);
  STG(sm.BH1a, gBa, ldb, 64);
  VMCNT(2);
  BARRIER();

  for (int J = 0; J < NIT; ++J) {
    const long k1 = 128L * J + 64;           // tile 2J+1
    const long k2 = 128L * J + 128;          // tile 2J+2
    const long k3 = 128L * J + 192;          // tile 2J+3
    const bool st = (J + 1 < NIT);

    // ---- K-tile T=2J (buf0): segments 0-1 ----
    RDB8(myB0); RDA4(myA0, 0);
    STG(sm.BH1b, gBb, ldb, k1);              // completes BH1 pair (read seg2)
    CLUSTER(0);
    RDA4(myA0, 1);
    STG(sm.AH1a, gAa, lda, k1);
    CLUSTER(1);
    BARRIER();

    RDA4(myA0, 2);
    STG(sm.AH1b, gAb, lda, k1);
    CLUSTER(2);
    RDA4(myA0, 3);
    if (st) STG(sm.BH0a, gBa, ldb, k2);
    CLUSTER(3);
    if (st) { VMCNT(2); } else { VMCNT(0); } // W1
    BARRIER();

    // ---- K-tile T+1 (buf1): segments 2-3 ----
    RDB8(myB1); RDA4(myA1, 0);
    if (st) STG(sm.BH0b, gBb, ldb, k2);
    CLUSTER(0);
    RDA4(myA1, 1);
    if (st) STG(sm.AH0a, gAa, lda, k2);
    CLUSTER(1);
    BARRIER();

    RDA4(myA1, 2);
    if (st) STG(sm.AH0b, gAb, lda, k2);
    CLUSTER(2);
    RDA4(myA1, 3);
    if (st) STG(sm.BH1a, gBa, ldb, k3);
    CLUSTER(3);
    if (st) VMCNT(2);                        // W2
    BARRIER();
  }

  // epilogue: C/D layout col = lane&15, row = (lane>>4)*4 + j
#pragma unroll
  for (int m = 0; m < 8; ++m) {
#pragma unroll
    for (int j = 0; j < 4; ++j) {
      const long row = brow + wr * 128 + m * 16 + lk * 4 + j;
      float inv = 0.f, part = 0.f;
      if (EPI == 3) inv = 1.0f / rs[row];
#pragma unroll
      for (int n = 0; n < 4; ++n) {
        const long col = bcol + wc * 64 + n * 16 + l15;
        const float a = acc[m][n][j];
        if (EPI == 1) {
          ((f16*)Cz)[row * (long)ldc + col] = (f16)(a * scale + (bias ? bias[col] : 0.f));
        } else if (EPI == 2) {
          const float e = __expf(a * scale);
          part += e;
          ((f16*)Cz)[row * (long)ldc + col] = (f16)e;
        } else {
          ((float*)Cz)[row * (long)ldc + col] = a * inv + bias[col];
        }
      }
      if (EPI == 2) {
        part += __shfl_xor(part, 1, 16);
        part += __shfl_xor(part, 2, 16);
        part += __shfl_xor(part, 4, 16);
        part += __shfl_xor(part, 8, 16);
        if (l15 == 0) atomicAdd(&rs[row], part);
      }
    }
  }
#undef STG
#undef RDA4
#undef RDB8
#undef CLUSTER
}

// QKV projection: f16 out + bias
__global__ __launch_bounds__(512, 2)
void gemm_qkv(const f16* __restrict__ Xh, const f16* __restrict__ Wqkvh,
              f16* __restrict__ QKV, const float* __restrict__ b_qkv)
{
  __shared__ Smem sm;
  gemm_body<1>(sm, Xh, 2048, Wqkvh, 2048, QKV, 6144, b_qkv, nullptr, 1.0f, 2048);
}

// fused: z<4 -> E_z = exp(Q_z K_z^T/sqrt(H)) + rowsum;  z>=4 -> VWT = Wout@V^T
__global__ __launch_bounds__(512, 2)
void gemm_sv(const f16* __restrict__ QKV, const f16* __restrict__ Wouth,
             f16* __restrict__ SCH, f16* __restrict__ VWT,
             float* __restrict__ RS, float inv_sqrt_h)
{
  __shared__ Smem sm;
  const int z = blockIdx.z;
  const long sQ = 2048L * 6144, sS = 2048L * 2048;
  if (z < 4) {
    gemm_body<2>(sm, QKV + z * sQ, 6144, QKV + 2048 + z * sQ, 6144,
                 SCH + z * sS, 2048, nullptr, RS + z * 2048, inv_sqrt_h, 2048);
  } else {
    const int zz = z - 4;
    gemm_body<1>(sm, Wouth, 2048, QKV + 4096 + zz * sQ, 6144,
                 VWT + zz * sS, 2048, nullptr, nullptr, 1.0f, 2048);
  }
}

// out[z][q][o] = (sum_s E[z][q][s]*VWT[z][o][s]) / rowsum[z][q] + b_out[o]
__global__ __launch_bounds__(512, 2)
void gemm_out(const f16* __restrict__ SCH, const f16* __restrict__ VWT,
              float* __restrict__ out, float* __restrict__ RS,
              const float* __restrict__ b_out)
{
  __shared__ Smem sm;
  const int z = blockIdx.z;
  const long sS = 2048L * 2048;
  gemm_body<3>(sm, SCH + z * sS, 2048, VWT + z * sS, 2048,
               out + z * sS, 2048, b_out, RS + z * 2048, 1.0f, 2048);
}

// all three f32->f16 casts + rowsum zeroing (block-range partition)
__global__ void cast_all(const float* __restrict__ x,     f16* __restrict__ xh,
                         const float* __restrict__ wq,    f16* __restrict__ wqh,
                         const float* __restrict__ wo,    f16* __restrict__ woh,
                         float* __restrict__ rs)
{
  const int b = blockIdx.x;
  if (b >= 4096) {                       // 4 blocks zero rowsum[4][2048]
    float4 z4 = {0.f, 0.f, 0.f, 0.f};
    float* p = rs + (long)(b - 4096) * 2048 + threadIdx.x * 8;
    *reinterpret_cast<float4*>(p) = z4;
    *reinterpret_cast<float4*>(p + 4) = z4;
    return;
  }
  const float* in; f16* out; long n; int b0, nb;
  if (b < 2048)      { in = x;  out = xh;  n = 16777216L; b0 = 0;    nb = 2048; }
  else if (b < 3584) { in = wq; out = wqh; n = 12582912L; b0 = 2048; nb = 1536; }
  else               { in = wo; out = woh; n = 4194304L;  b0 = 3584; nb = 512;  }
  long i = ((long)(b - b0) * 256 + threadIdx.x) * 4;
  const long stride = (long)nb * 256 * 4;
  for (; i < n; i += stride) {
    const float4 v = *reinterpret_cast<const float4*>(in + i);
    f16x4 h;
    h.x = (f16)v.x; h.y = (f16)v.y; h.z = (f16)v.z; h.w = (f16)v.w;
    *reinterpret_cast<f16x4*>(out + i) = h;
  }
}

extern "C" void kernel_launch(void* const* d_in, const int* in_sizes, int n_in,
                              void* d_out, int out_size, void* d_ws, size_t ws_size,
                              hipStream_t stream) {
  const float* x     = (const float*)d_in[0];  // [4,2048,2048]
  const float* w_qkv = (const float*)d_in[1];  // [6144,2048]
  const float* b_qkv = (const float*)d_in[2];  // [6144]
  const float* w_out = (const float*)d_in[3];  // [2048,2048]
  const float* b_out = (const float*)d_in[4];  // [2048]
  float* out = (float*)d_out;                  // [4,2048,2048] f32

  char* ws = (char*)d_ws;
  f16*   Xh    = (f16*)(ws + 0);           //  33.5 MB  [8192][2048]; dead after
                                           //  QKV gemm -> reused as SCH
  f16*   Wqkvh = (f16*)(ws + 33554432L);   //  25.2 MB  [6144][2048]
  f16*   Wouth = (f16*)(ws + 58720256L);   //   8.4 MB  [2048][2048]
  f16*   QKV   = (f16*)(ws + 67108864L);   // 100.7 MB  [8192][6144]
  float* RS    = (float*)(ws + 167772160L);//  32 KB    [4][2048] rowsums
  f16*   VWT   = (f16*)(ws + 234881024L);  //  33.5 MB  [4][2048 o][2048 s]
  f16*   SCH   = Xh;                       //  33.5 MB  E = exp(scores), f16

  const float inv_sqrt_h = 0.022097086912079608f;  // 1/sqrt(2048)

  cast_all<<<4100, 256, 0, stream>>>(x, Xh, w_qkv, Wqkvh, w_out, Wouth, RS);

  // qkv = x @ w_qkv^T + b_qkv   [8192 x 6144]
  gemm_qkv<<<dim3(24, 32, 1), 512, 0, stream>>>(Xh, Wqkvh, QKV, b_qkv);

  // fused: E + rowsum (z<4), VWT (z>=4)
  gemm_sv<<<dim3(8, 8, 8), 512, 0, stream>>>(QKV, Wouth, SCH, VWT, RS, inv_sqrt_h);

  // out = (E @ VWT^T) / rowsum + b_out
  gemm_out<<<dim3(8, 8, 4), 512, 0, stream>>>(SCH, VWT, out, RS, b_out);
}

// Round 20
// 411.626 us; speedup vs baseline: 1.0840x; 1.0840x over previous
//
#include <hip/hip_runtime.h>
#include <cstdint>

typedef _Float16 f16;
typedef __attribute__((ext_vector_type(8))) _Float16 f16x8;
typedef __attribute__((ext_vector_type(4))) _Float16 f16x4;
typedef __attribute__((ext_vector_type(4))) float f32x4;

typedef __attribute__((address_space(1))) void gvoid_t;
typedef __attribute__((address_space(3))) void lvoid_t;

// async global->LDS, 16B per lane. LDS dest wave-uniform base; HW adds lane*16.
__device__ __forceinline__ void async_copy16(void* lds, const void* g) {
  __builtin_amdgcn_global_load_lds((gvoid_t*)(uintptr_t)g, (lvoid_t*)lds, 16, 0, 0);
}

#define BARRIER()   __builtin_amdgcn_s_barrier()
#define SCHEDBAR()  __builtin_amdgcn_sched_barrier(0)
#define VMCNT(n)    do { SCHEDBAR(); asm volatile("s_waitcnt vmcnt(" #n ")"); SCHEDBAR(); } while (0)

#define MFMA16(a, b, c) __builtin_amdgcn_mfma_f32_16x16x32_f16((a), (b), (c), 0, 0, 0)

// ----------------- shared helpers (addressing + schedule macros) -----------

#define GEOM_DECLS \
  const int tid = threadIdx.x, lane = tid & 63, wave = tid >> 6;               \
  const int wr = wave >> 2, wc = wave & 3;                                     \
  const int l15 = lane & 15, lk = lane >> 4;                                   \
  int lin = blockIdx.y * gridDim.x + blockIdx.x;                               \
  const int nxy = gridDim.x * gridDim.y;                                       \
  if ((nxy & 7) == 0) lin = (lin & 7) * (nxy >> 3) + (lin >> 3);               \
  const int bx = lin % gridDim.x, by = lin / gridDim.x;                        \
  const long brow = (long)by * 256, bcol = (long)bx * 256;                     \
  const int r0  = tid >> 3;                                                    \
  const int gc8 = (tid & 7) ^ (r0 & 7);                                        \
  const int sdst = wave * 512;                                                 \
  const f16* gAa = Ab + (brow + r0) * (long)lda + gc8 * 8;                     \
  const f16* gAb = gAa + 128L * lda;                                           \
  const f16* gBa = Bb + (bcol + r0) * (long)ldb + gc8 * 8;                     \
  const f16* gBb = gBa + 128L * ldb;                                           \
  const int x8   = l15 & 7;                                                    \
  const int cb0  = (lk ^ x8) * 8;                                              \
  const int cb1  = ((4 | lk) ^ x8) * 8;                                        \
  const int lbA  = l15 * 64;                                                   \
  const int lbB  = ((wc & 1) * 64 + l15) * 64;

#define STG(BUF, G, LD, KOFF) { \
    async_copy16((BUF) + sdst,        (G) + (KOFF)); \
    async_copy16((BUF) + 4096 + sdst, (G) + 64L * (LD) + (KOFF)); }

#define RDA4(SRC, MP) { \
    af[0] = *(const f16x8*)&(SRC)[lbA + (2*(MP))   * 1024 + cb0]; \
    af[1] = *(const f16x8*)&(SRC)[lbA + (2*(MP))   * 1024 + cb1]; \
    af[2] = *(const f16x8*)&(SRC)[lbA + (2*(MP)+1) * 1024 + cb0]; \
    af[3] = *(const f16x8*)&(SRC)[lbA + (2*(MP)+1) * 1024 + cb1]; }

#define RDB8(SRC) { \
    bf[0][0] = *(const f16x8*)&(SRC)[lbB + 0 * 1024 + cb0]; \
    bf[1][0] = *(const f16x8*)&(SRC)[lbB + 0 * 1024 + cb1]; \
    bf[0][1] = *(const f16x8*)&(SRC)[lbB + 1 * 1024 + cb0]; \
    bf[1][1] = *(const f16x8*)&(SRC)[lbB + 1 * 1024 + cb1]; \
    bf[0][2] = *(const f16x8*)&(SRC)[lbB + 2 * 1024 + cb0]; \
    bf[1][2] = *(const f16x8*)&(SRC)[lbB + 2 * 1024 + cb1]; \
    bf[0][3] = *(const f16x8*)&(SRC)[lbB + 3 * 1024 + cb0]; \
    bf[1][3] = *(const f16x8*)&(SRC)[lbB + 3 * 1024 + cb1]; }

#define CLUSTER(MP) { \
    __builtin_amdgcn_s_setprio(1); \
    _Pragma("unroll") \
    for (int n = 0; n < 4; ++n) { \
      f32x4 t = MFMA16(af[0], bf[0][n], acc[2*(MP)][n]); \
      acc[2*(MP)][n] = MFMA16(af[1], bf[1][n], t); \
    } \
    _Pragma("unroll") \
    for (int n = 0; n < 4; ++n) { \
      f32x4 t = MFMA16(af[2], bf[0][n], acc[2*(MP)+1][n]); \
      acc[2*(MP)+1][n] = MFMA16(af[3], bf[1][n], t); \
    } \
    __builtin_amdgcn_s_setprio(0); }

// main loop (r16/r17 converged schedule): 4 barrier-segments per 2 K-tiles
#define MAIN_LOOP(A0, A1, B0, B1, SBH1b, SAH1a, SAH1b, SBH0a, SBH0b, SAH0a, SAH0b, SBH1a) \
  for (int J = 0; J < NIT; ++J) {                                              \
    const long k1 = 128L * J + 64;                                             \
    const long k2 = 128L * J + 128;                                            \
    const long k3 = 128L * J + 192;                                            \
    const bool st = (J + 1 < NIT);                                             \
    RDB8(B0); RDA4(A0, 0);                                                     \
    STG(SBH1b, gBb, ldb, k1);                                                  \
    CLUSTER(0);                                                                \
    RDA4(A0, 1);                                                               \
    STG(SAH1a, gAa, lda, k1);                                                  \
    CLUSTER(1);                                                                \
    BARRIER();                                                                 \
    RDA4(A0, 2);                                                               \
    STG(SAH1b, gAb, lda, k1);                                                  \
    CLUSTER(2);                                                                \
    RDA4(A0, 3);                                                               \
    if (st) STG(SBH0a, gBa, ldb, k2);                                          \
    CLUSTER(3);                                                                \
    if (st) { VMCNT(2); } else { VMCNT(0); }                                   \
    BARRIER();                                                                 \
    RDB8(B1); RDA4(A1, 0);                                                     \
    if (st) STG(SBH0b, gBb, ldb, k2);                                          \
    CLUSTER(0);                                                                \
    RDA4(A1, 1);                                                               \
    if (st) STG(SAH0a, gAa, lda, k2);                                          \
    CLUSTER(1);                                                                \
    BARRIER();                                                                 \
    RDA4(A1, 2);                                                               \
    if (st) STG(SAH0b, gAb, lda, k2);                                          \
    CLUSTER(2);                                                                \
    RDA4(A1, 3);                                                               \
    if (st) STG(SBH1a, gBa, ldb, k3);                                          \
    CLUSTER(3);                                                                \
    if (st) VMCNT(2);                                                          \
    BARRIER();                                                                 \
  }

#define PROLOGUE(SBH0a, SBH0b, SAH0a, SAH0b, SBH1a) \
  STG(SBH0a, gBa, ldb, 0);  STG(SBH0b, gBb, ldb, 0);                           \
  STG(SAH0a, gAa, lda, 0);  STG(SAH0b, gAb, lda, 0);                           \
  STG(SBH1a, gBa, ldb, 64);                                                    \
  VMCNT(2);                                                                    \
  BARRIER();

// --------- r16-verbatim QKV kernel (in-body __shared__, clean codegen) -----
__global__ __launch_bounds__(512, 2)
void gemm_qkv(const f16* __restrict__ Ab, const f16* __restrict__ Bb,
              f16* __restrict__ Cz, const float* __restrict__ bias)
{
  __shared__ f16 AH0a[8192]; __shared__ f16 AH0b[8192];
  __shared__ f16 AH1a[8192]; __shared__ f16 AH1b[8192];
  __shared__ f16 BH0a[8192]; __shared__ f16 BH0b[8192];
  __shared__ f16 BH1a[8192]; __shared__ f16 BH1b[8192];
  const int lda = 2048, ldb = 2048, ldc = 6144;
  GEOM_DECLS
  const f16* myA0 = wr ? AH0b : AH0a;
  const f16* myA1 = wr ? AH1b : AH1a;
  const f16* myB0 = (wc & 2) ? BH0b : BH0a;
  const f16* myB1 = (wc & 2) ? BH1b : BH1a;

  f32x4 acc[8][4] = {};
  f16x8 af[4], bf[2][4];
  const int NIT = 16;                        // K=2048
  PROLOGUE(BH0a, BH0b, AH0a, AH0b, BH1a)
  MAIN_LOOP(myA0, myA1, myB0, myB1, BH1b, AH1a, AH1b, BH0a, BH0b, AH0a, AH0b, BH1a)

#pragma unroll
  for (int m = 0; m < 8; ++m) {
#pragma unroll
    for (int n = 0; n < 4; ++n) {
      const long col = bcol + wc * 64 + n * 16 + l15;
      const float bv = bias[col];
#pragma unroll
      for (int j = 0; j < 4; ++j) {
        const long row = brow + wr * 128 + m * 16 + lk * 4 + j;
        Cz[row * (long)ldc + col] = (f16)(acc[m][n][j] + bv);
      }
    }
  }
}

// --------- Smem-struct body for the fused kernels --------------------------
struct Smem {
  f16 AH0a[8192]; f16 AH0b[8192];
  f16 AH1a[8192]; f16 AH1b[8192];
  f16 BH0a[8192]; f16 BH0b[8192];
  f16 BH1a[8192]; f16 BH1b[8192];
};

// EPI=1: f16 = acc*scale; EPI=2: f16 = exp(acc*scale) + rowsum atomics;
// EPI=3: f32 = acc / rs[row] + bias[col]
template<int EPI>
__device__ __forceinline__ void gemm_body(Smem& sm,
                                          const f16* __restrict__ Ab, int lda,
                                          const f16* __restrict__ Bb, int ldb,
                                          void* __restrict__ Cz, int ldc,
                                          const float* __restrict__ bias,
                                          float* __restrict__ rs,
                                          float scale, int K)
{
  GEOM_DECLS
  const f16* myA0 = wr ? sm.AH0b : sm.AH0a;
  const f16* myA1 = wr ? sm.AH1b : sm.AH1a;
  const f16* myB0 = (wc & 2) ? sm.BH0b : sm.BH0a;
  const f16* myB1 = (wc & 2) ? sm.BH1b : sm.BH1a;

  f32x4 acc[8][4] = {};
  f16x8 af[4], bf[2][4];
  const int NIT = K >> 7;
  PROLOGUE(sm.BH0a, sm.BH0b, sm.AH0a, sm.AH0b, sm.BH1a)
  MAIN_LOOP(myA0, myA1, myB0, myB1, sm.BH1b, sm.AH1a, sm.AH1b, sm.BH0a,
            sm.BH0b, sm.AH0a, sm.AH0b, sm.BH1a)

#pragma unroll
  for (int m = 0; m < 8; ++m) {
#pragma unroll
    for (int j = 0; j < 4; ++j) {
      const long row = brow + wr * 128 + m * 16 + lk * 4 + j;
      float inv = 0.f, part = 0.f;
      if (EPI == 3) inv = 1.0f / rs[row];
#pragma unroll
      for (int n = 0; n < 4; ++n) {
        const long col = bcol + wc * 64 + n * 16 + l15;
        const float a = acc[m][n][j];
        if (EPI == 1) {
          ((f16*)Cz)[row * (long)ldc + col] = (f16)(a * scale);
        } else if (EPI == 2) {
          const float e = __expf(a * scale);
          part += e;
          ((f16*)Cz)[row * (long)ldc + col] = (f16)e;
        } else {
          ((float*)Cz)[row * (long)ldc + col] = a * inv + bias[col];
        }
      }
      if (EPI == 2) {
        part += __shfl_xor(part, 1, 16);
        part += __shfl_xor(part, 2, 16);
        part += __shfl_xor(part, 4, 16);
        part += __shfl_xor(part, 8, 16);
        if (l15 == 0) atomicAdd(&rs[row], part);
      }
    }
  }
}

// fused: z<4 -> E_z = exp(Q_z K_z^T/sqrt(H)) + rowsum;  z>=4 -> VWT = Wout@V^T
__global__ __launch_bounds__(512, 2)
void gemm_sv(const f16* __restrict__ QKV, const f16* __restrict__ Wouth,
             f16* __restrict__ SCH, f16* __restrict__ VWT,
             float* __restrict__ RS, float inv_sqrt_h)
{
  __shared__ Smem sm;
  const int z = blockIdx.z;
  const long sQ = 2048L * 6144, sS = 2048L * 2048;
  if (z < 4) {
    gemm_body<2>(sm, QKV + z * sQ, 6144, QKV + 2048 + z * sQ, 6144,
                 SCH + z * sS, 2048, nullptr, RS + z * 2048, inv_sqrt_h, 2048);
  } else {
    const int zz = z - 4;
    gemm_body<1>(sm, Wouth, 2048, QKV + 4096 + zz * sQ, 6144,
                 VWT + zz * sS, 2048, nullptr, nullptr, 1.0f, 2048);
  }
}

// out[z][q][o] = (sum_s E[z][q][s]*VWT[z][o][s]) / rowsum[z][q] + b_out[o]
__global__ __launch_bounds__(512, 2)
void gemm_out(const f16* __restrict__ SCH, const f16* __restrict__ VWT,
              float* __restrict__ out, float* __restrict__ RS,
              const float* __restrict__ b_out)
{
  __shared__ Smem sm;
  const int z = blockIdx.z;
  const long sS = 2048L * 2048;
  gemm_body<3>(sm, SCH + z * sS, 2048, VWT + z * sS, 2048,
               out + z * sS, 2048, b_out, RS + z * 2048, 1.0f, 2048);
}

// all three f32->f16 casts + rowsum zeroing (block-range partition)
__global__ void cast_all(const float* __restrict__ x,     f16* __restrict__ xh,
                         const float* __restrict__ wq,    f16* __restrict__ wqh,
                         const float* __restrict__ wo,    f16* __restrict__ woh,
                         float* __restrict__ rs)
{
  const int b = blockIdx.x;
  if (b >= 4096) {                       // 4 blocks zero rowsum[4][2048]
    float4 z4 = {0.f, 0.f, 0.f, 0.f};
    float* p = rs + (long)(b - 4096) * 2048 + threadIdx.x * 8;
    *reinterpret_cast<float4*>(p) = z4;
    *reinterpret_cast<float4*>(p + 4) = z4;
    return;
  }
  const float* in; f16* out; long n; int b0, nb;
  if (b < 2048)      { in = x;  out = xh;  n = 16777216L; b0 = 0;    nb = 2048; }
  else if (b < 3584) { in = wq; out = wqh; n = 12582912L; b0 = 2048; nb = 1536; }
  else               { in = wo; out = woh; n = 4194304L;  b0 = 3584; nb = 512;  }
  long i = ((long)(b - b0) * 256 + threadIdx.x) * 4;
  const long stride = (long)nb * 256 * 4;
  for (; i < n; i += stride) {
    const float4 v = *reinterpret_cast<const float4*>(in + i);
    f16x4 h;
    h.x = (f16)v.x; h.y = (f16)v.y; h.z = (f16)v.z; h.w = (f16)v.w;
    *reinterpret_cast<f16x4*>(out + i) = h;
  }
}

extern "C" void kernel_launch(void* const* d_in, const int* in_sizes, int n_in,
                              void* d_out, int out_size, void* d_ws, size_t ws_size,
                              hipStream_t stream) {
  const float* x     = (const float*)d_in[0];  // [4,2048,2048]
  const float* w_qkv = (const float*)d_in[1];  // [6144,2048]
  const float* b_qkv = (const float*)d_in[2];  // [6144]
  const float* w_out = (const float*)d_in[3];  // [2048,2048]
  const float* b_out = (const float*)d_in[4];  // [2048]
  float* out = (float*)d_out;                  // [4,2048,2048] f32

  char* ws = (char*)d_ws;
  f16*   Xh    = (f16*)(ws + 0);           //  33.5 MB; dead after QKV -> SCH
  f16*   Wqkvh = (f16*)(ws + 33554432L);   //  25.2 MB
  f16*   Wouth = (f16*)(ws + 58720256L);   //   8.4 MB
  f16*   QKV   = (f16*)(ws + 67108864L);   // 100.7 MB  [8192][6144]
  float* RS    = (float*)(ws + 167772160L);//  32 KB    [4][2048] rowsums
  f16*   VWT   = (f16*)(ws + 234881024L);  //  33.5 MB  [4][2048 o][2048 s]
  f16*   SCH   = Xh;                       //  33.5 MB  E = exp(scores), f16

  const float inv_sqrt_h = 0.022097086912079608f;  // 1/sqrt(2048)

  cast_all<<<4100, 256, 0, stream>>>(x, Xh, w_qkv, Wqkvh, w_out, Wouth, RS);

  // qkv = x @ w_qkv^T + b_qkv   [8192 x 6144], grid (24,32)
  gemm_qkv<<<dim3(24, 32, 1), 512, 0, stream>>>(Xh, Wqkvh, QKV, b_qkv);

  // fused: E + rowsum (z<4), VWT (z>=4)
  gemm_sv<<<dim3(8, 8, 8), 512, 0, stream>>>(QKV, Wouth, SCH, VWT, RS, inv_sqrt_h);

  // out = (E @ VWT^T) / rowsum + b_out
  gemm_out<<<dim3(8, 8, 4), 512, 0, stream>>>(SCH, VWT, out, RS, b_out);
}